// Round 7
// baseline (195.214 us; speedup 1.0000x reference)
//
#include <hip/hip_runtime.h>

// Problem constants (B=2, H=4 -> NBH=8; Tq=Tk=512; D=64; HID=128)
#define T    512
#define D    64
#define HID  128
#define NBH  8
#define NP   (HID / 2)   // 64 c-pairs

typedef _Float16 h2 __attribute__((ext_vector_type(2)));

static __device__ __forceinline__ h2 bc_h2(float f) {
    return __builtin_bit_cast(h2, f);
}

// ---------------------------------------------------------------------------
// INSTRUMENTATION ROUND: both kernels carry a runtime `reps` multiplier so
// their dispatches exceed the ~43 us harness-fill cutoff and appear in the
// rocprof top-5 with real counters (first direct measurement this session).
// proj: rep loop re-runs compute+store (stores are side effects; reps is a
// runtime arg -> no elision). score: accumulator carried ACROSS reps (true
// data dependence), output scaled by 1/reps (exact for reps=8).
// unit times: proj_row/24, score_row/8.
// ---------------------------------------------------------------------------

__global__ __launch_bounds__(256, 2) void proj_kernel(
    const float* __restrict__ q, const float* __restrict__ k,
    const float* __restrict__ W1, const float* __restrict__ b1,
    h2* __restrict__ qh_h, h2* __restrict__ kh_h, int reps)
{
    const int bid    = blockIdx.x;        // [0,512)
    const int bh     = bid >> 6;
    const int src    = (bid >> 5) & 1;
    const int chunk  = (bid >> 2) & 7;
    const int csplit = bid & 3;
    const int base_c = csplit * 32;       // 32 channels per block

    const float* __restrict__ X = (src == 0) ? q : k;
    h2* __restrict__ outp       = (src == 0) ? qh_h : kh_h;

    __shared__ float w1t[32][68];

    const int tid = threadIdx.x;
    for (int idx = tid; idx < 32 * 64; idx += 256) {
        const int cc = idx & 31;
        const int d  = idx >> 5;
        w1t[cc][d] = W1[(src * D + d) * HID + base_c + cc];
    }
    __syncthreads();

    const int r  = tid & 63;
    const int cg = tid >> 6;
    const int i  = chunk * 64 + r;

    float xr[D];
    const float4* xrow = (const float4*)(X + (size_t)(bh * T + i) * D);
    #pragma unroll
    for (int t = 0; t < D / 4; ++t) {
        const float4 v = xrow[t];
        xr[4*t+0] = v.x; xr[4*t+1] = v.y; xr[4*t+2] = v.z; xr[4*t+3] = v.w;
    }

    for (int rep = 0; rep < reps; ++rep) {
        #pragma unroll
        for (int pp = 0; pp < 4; ++pp) {
            const int cc0 = cg * 8 + 2 * pp;
            float acc0 = (src == 0) ? b1[base_c + cc0]     : 0.0f;
            float acc1 = (src == 0) ? b1[base_c + cc0 + 1] : 0.0f;
            const float4* w0 = (const float4*)(&w1t[cc0][0]);
            const float4* w1 = (const float4*)(&w1t[cc0 + 1][0]);
            #pragma unroll
            for (int t = 0; t < D / 4; ++t) {
                const float4 a = w0[t];
                const float4 b = w1[t];
                acc0 += xr[4*t+0]*a.x + xr[4*t+1]*a.y + xr[4*t+2]*a.z + xr[4*t+3]*a.w;
                acc1 += xr[4*t+0]*b.x + xr[4*t+1]*b.y + xr[4*t+2]*b.z + xr[4*t+3]*b.w;
            }
            h2 v;
            v.x = (_Float16)acc0;
            v.y = (_Float16)acc1;
            const int p = csplit * 16 + cg * 4 + pp;
            outp[(size_t)(bh * NP + p) * T + i] = v;
        }
    }
}

__global__ __launch_bounds__(256, 2) void score_kernel(
    const h2* __restrict__ qh_h, const h2* __restrict__ kh_h,
    const float* __restrict__ W2, const float* __restrict__ b2,
    float* __restrict__ out, int reps, float inv_reps)
{
    const int bid = blockIdx.x;           // [0, 512)
    const int bh  = bid >> 6;
    const int it  = (bid >> 3) & 7;
    const int jt  = bid & 7;
    const int i0  = it * 64;
    const int j0  = jt * 64;

    __shared__ h2 qt2[NP][64];            // 16 KB
    __shared__ h2 kt2[NP][64];            // 16 KB
    __shared__ h2 w2h[NP];                // 256 B

    const int tid = threadIdx.x;
    for (int idx = tid; idx < 2 * NP * 16; idx += 256) {
        const int tile = idx >> 10;
        const int p    = (idx >> 4) & 63;
        const int g    = idx & 15;
        const h2* srcp = tile ? kh_h : qh_h;
        const int o0   = tile ? j0 : i0;
        float4 v = ((const float4*)(srcp + (size_t)(bh * NP + p) * T + o0))[g];
        if (tile) ((float4*)&kt2[p][0])[g] = v;
        else      ((float4*)&qt2[p][0])[g] = v;
    }
    if (tid < NP) {
        h2 w;
        w.x = (_Float16)W2[2 * tid];
        w.y = (_Float16)W2[2 * tid + 1];
        w2h[tid] = w;
    }
    __syncthreads();

    const int tx = tid & 15;              // j fragment (4 j's)
    const int ty = tid >> 4;              // i fragment (4 i's)

    float acc[4][4];
    #pragma unroll
    for (int m = 0; m < 4; ++m)
        #pragma unroll
        for (int n = 0; n < 4; ++n)
            acc[m][n] = 0.0f;

    // acc carried across reps -> every rep's dot2 chain is data-dependent on
    // the previous one; no elision possible. Final scale by 1/reps (exact).
    for (int rep = 0; rep < reps; ++rep) {
        for (int pg = 0; pg < 16; ++pg) {
            const float4 w4 = ((const float4*)&w2h[0])[pg];
            #pragma unroll
            for (int s = 0; s < 4; ++s) {
                const int p = 4 * pg + s;
                const h2 w = bc_h2(s == 0 ? w4.x : s == 1 ? w4.y
                                 : s == 2 ? w4.z : w4.w);
                const float4 qa4 = ((const float4*)&qt2[p][0])[ty];
                const float4 kb4 = ((const float4*)&kt2[p][0])[tx];
                const h2 qv[4] = {bc_h2(qa4.x), bc_h2(qa4.y),
                                  bc_h2(qa4.z), bc_h2(qa4.w)};
                const h2 kv[4] = {bc_h2(kb4.x), bc_h2(kb4.y),
                                  bc_h2(kb4.z), bc_h2(kb4.w)};
                #pragma unroll
                for (int m = 0; m < 4; ++m) {
                    #pragma unroll
                    for (int n = 0; n < 4; ++n) {
                        h2 u, rr;
                        asm("v_pk_add_f16 %0, %1, %2"
                            : "=v"(u) : "v"(qv[m]), "v"(kv[n]));
                        asm("v_pk_max_f16 %0, %1, 0"
                            : "=v"(rr) : "v"(u));
                        asm("v_dot2_f32_f16 %0, %1, %2, %0"
                            : "+v"(acc[m][n]) : "v"(rr), "v"(w));
                    }
                }
            }
        }
    }

    const float bb = b2[0];
    #pragma unroll
    for (int m = 0; m < 4; ++m) {
        const int i = i0 + 4 * ty + m;
        float4 o;
        o.x = acc[m][0] * inv_reps + bb;
        o.y = acc[m][1] * inv_reps + bb;
        o.z = acc[m][2] * inv_reps + bb;
        o.w = acc[m][3] * inv_reps + bb;
        ((float4*)(out + (size_t)(bh * T + i) * T + j0))[tx] = o;
    }
}

extern "C" void kernel_launch(void* const* d_in, const int* in_sizes, int n_in,
                              void* d_out, int out_size, void* d_ws, size_t ws_size,
                              hipStream_t stream) {
    const float* q  = (const float*)d_in[0];
    const float* k  = (const float*)d_in[1];
    const float* W1 = (const float*)d_in[2];
    const float* b1 = (const float*)d_in[3];
    const float* W2 = (const float*)d_in[4];
    const float* b2 = (const float*)d_in[5];
    float* out = (float*)d_out;

    h2* qh_h = (h2*)d_ws;
    h2* kh_h = qh_h + (size_t)NBH * NP * T;

    // Instrumentation multipliers: both kernels must exceed the ~43 us
    // harness-fill cutoff to appear in rocprof top-5 with counters.
    proj_kernel<<<512, 256, 0, stream>>>(q, k, W1, b1, qh_h, kh_h, 24);
    score_kernel<<<512, 256, 0, stream>>>(qh_h, kh_h, W2, b2, out, 8, 0.125f);
}

// Round 8
// 92.574 us; speedup vs baseline: 2.1087x; 2.1087x over previous
//
#include <hip/hip_runtime.h>

// Problem constants (B=2, H=4 -> NBH=8; Tq=Tk=512; D=64; HID=128)
#define T    512
#define D    64
#define HID  128
#define NBH  8
#define NP   (HID / 2)   // 64 c-pairs

typedef _Float16 h2 __attribute__((ext_vector_type(2)));

static __device__ __forceinline__ h2 bc_h2(float f) {
    return __builtin_bit_cast(h2, f);
}

// ---------------------------------------------------------------------------
// Phase A (R3/R6 best-measured version): LDS-staged W1.
// qh[bh][c][i] = b1[c] + sum_d q[bh][i][d] * W1[d][c]   (src==0)
// kh[bh][c][j] =         sum_d k[bh][j][d] * W1[64+d][c] (src==1)
// Output packed as h2 pairs over c: ws[bh][p][i], i contiguous.
// grid: 8 bh x 2 src x 8 row-chunks x 4 c-splits = 512 blocks (2/CU).
// Measured (R7 arithmetic): ~3 us total — not the target.
// ---------------------------------------------------------------------------
__global__ __launch_bounds__(256, 2) void proj_kernel(
    const float* __restrict__ q, const float* __restrict__ k,
    const float* __restrict__ W1, const float* __restrict__ b1,
    h2* __restrict__ qh_h, h2* __restrict__ kh_h)
{
    const int bid    = blockIdx.x;        // [0,512)
    const int bh     = bid >> 6;
    const int src    = (bid >> 5) & 1;
    const int chunk  = (bid >> 2) & 7;
    const int csplit = bid & 3;
    const int base_c = csplit * 32;       // 32 channels per block

    const float* __restrict__ X = (src == 0) ? q : k;
    h2* __restrict__ outp       = (src == 0) ? qh_h : kh_h;

    __shared__ float w1t[32][68];

    const int tid = threadIdx.x;
    for (int idx = tid; idx < 32 * 64; idx += 256) {
        const int cc = idx & 31;
        const int d  = idx >> 5;
        w1t[cc][d] = W1[(src * D + d) * HID + base_c + cc];
    }
    __syncthreads();

    const int r  = tid & 63;
    const int cg = tid >> 6;
    const int i  = chunk * 64 + r;

    float xr[D];
    const float4* xrow = (const float4*)(X + (size_t)(bh * T + i) * D);
    #pragma unroll
    for (int t = 0; t < D / 4; ++t) {
        const float4 v = xrow[t];
        xr[4*t+0] = v.x; xr[4*t+1] = v.y; xr[4*t+2] = v.z; xr[4*t+3] = v.w;
    }

    #pragma unroll
    for (int pp = 0; pp < 4; ++pp) {
        const int cc0 = cg * 8 + 2 * pp;
        float acc0 = (src == 0) ? b1[base_c + cc0]     : 0.0f;
        float acc1 = (src == 0) ? b1[base_c + cc0 + 1] : 0.0f;
        const float4* w0 = (const float4*)(&w1t[cc0][0]);
        const float4* w1 = (const float4*)(&w1t[cc0 + 1][0]);
        #pragma unroll
        for (int t = 0; t < D / 4; ++t) {
            const float4 a = w0[t];
            const float4 b = w1[t];
            acc0 += xr[4*t+0]*a.x + xr[4*t+1]*a.y + xr[4*t+2]*a.z + xr[4*t+3]*a.w;
            acc1 += xr[4*t+0]*b.x + xr[4*t+1]*b.y + xr[4*t+2]*b.z + xr[4*t+3]*b.w;
        }
        h2 v;
        v.x = (_Float16)acc0;
        v.y = (_Float16)acc1;
        const int p = csplit * 16 + cg * 4 + pp;
        outp[(size_t)(bh * NP + p) * T + i] = v;
    }
}

// ---------------------------------------------------------------------------
// Phase B: s[bh][i][j] = b2 + sum_c W2[c] * relu(qh[bh][c][i] + kh[bh][c][j])
// OVERLAP EXPERIMENT (R7 counters: score=14.4us vs 5.1 VALU + 5.1 LDS pipe
// floors; overlap-limited, 2 barrier domains/CU). New geometry: 64x32 tile,
// 128-thread blocks, grid 1024 -> 4 blocks/CU (4 independent barrier
// domains), still 8 waves/CU, LDS 24.3 KB. Both operands remain b128 with
// 8-way same-address broadcast (free) — avoids R4's b64-k mistake.
// frag 4x4 per thread: tx in [0,8) j-quads, ty in [0,16) i-quads.
// Inner asm: v_pk_add_f16 + v_pk_max_f16 + v_dot2_f32_f16 (3 instr/2 MACs).
// grid: 8 bh x 8 it x 16 jt = 1024 blocks.
// ---------------------------------------------------------------------------
__global__ __launch_bounds__(128, 2) void score_kernel(
    const h2* __restrict__ qh_h, const h2* __restrict__ kh_h,
    const float* __restrict__ W2, const float* __restrict__ b2,
    float* __restrict__ out)
{
    const int bid = blockIdx.x;           // [0, 1024)
    const int bh  = bid >> 7;
    const int it  = (bid >> 4) & 7;
    const int jt  = bid & 15;
    const int i0  = it * 64;
    const int j0  = jt * 32;

    __shared__ h2 qt2[NP][64];            // 16 KB, row 256 B
    __shared__ h2 kt2[NP][32];            // 8 KB,  row 128 B
    __shared__ h2 w2h[NP];                // 256 B

    const int tid = threadIdx.x;          // [0,128)
    // Stage q-tile: 64 rows x 16 float4 (256 B coalesced per row).
    for (int idx = tid; idx < NP * 16; idx += 128) {
        const int p = idx >> 4;
        const int g = idx & 15;
        ((float4*)&qt2[p][0])[g] =
            ((const float4*)(qh_h + (size_t)(bh * NP + p) * T + i0))[g];
    }
    // Stage k-tile: 64 rows x 8 float4 (128 B per row).
    for (int idx = tid; idx < NP * 8; idx += 128) {
        const int p = idx >> 3;
        const int g = idx & 7;
        ((float4*)&kt2[p][0])[g] =
            ((const float4*)(kh_h + (size_t)(bh * NP + p) * T + j0))[g];
    }
    if (tid < NP) {
        h2 w;
        w.x = (_Float16)W2[2 * tid];
        w.y = (_Float16)W2[2 * tid + 1];
        w2h[tid] = w;
    }
    __syncthreads();

    const int tx = tid & 7;               // j quad: j = j0 + 4*tx + n
    const int ty = tid >> 3;              // i quad: i = i0 + 4*ty + m

    float acc[4][4];
    #pragma unroll
    for (int m = 0; m < 4; ++m)
        #pragma unroll
        for (int n = 0; n < 4; ++n)
            acc[m][n] = 0.0f;

    for (int pg = 0; pg < 16; ++pg) {
        // One b128 per 4 c-pairs for the w2 values.
        const float4 w4 = ((const float4*)&w2h[0])[pg];
        #pragma unroll
        for (int s = 0; s < 4; ++s) {
            const int p = 4 * pg + s;
            const h2 w = bc_h2(s == 0 ? w4.x : s == 1 ? w4.y
                             : s == 2 ? w4.z : w4.w);
            // 8 distinct addrs/wave, each 8-way broadcast: conflict-free.
            const float4 qa4 = ((const float4*)&qt2[p][0])[ty];  // 4 h2: i..i+3
            const float4 kb4 = ((const float4*)&kt2[p][0])[tx];  // 4 h2: j..j+3
            const h2 qv[4] = {bc_h2(qa4.x), bc_h2(qa4.y),
                              bc_h2(qa4.z), bc_h2(qa4.w)};
            const h2 kv[4] = {bc_h2(kb4.x), bc_h2(kb4.y),
                              bc_h2(kb4.z), bc_h2(kb4.w)};
            #pragma unroll
            for (int m = 0; m < 4; ++m) {
                #pragma unroll
                for (int n = 0; n < 4; ++n) {
                    h2 u, rr;
                    asm("v_pk_add_f16 %0, %1, %2"
                        : "=v"(u) : "v"(qv[m]), "v"(kv[n]));
                    asm("v_pk_max_f16 %0, %1, 0"
                        : "=v"(rr) : "v"(u));
                    asm("v_dot2_f32_f16 %0, %1, %2, %0"
                        : "+v"(acc[m][n]) : "v"(rr), "v"(w));
                }
            }
        }
    }

    const float bb = b2[0];
    #pragma unroll
    for (int m = 0; m < 4; ++m) {
        const int i = i0 + 4 * ty + m;
        float4 o;
        o.x = acc[m][0] + bb;
        o.y = acc[m][1] + bb;
        o.z = acc[m][2] + bb;
        o.w = acc[m][3] + bb;
        // 8 lanes x 16 B contiguous per (ty,m) sub-row.
        ((float4*)(out + (size_t)(bh * T + i) * T + j0))[tx] = o;
    }
}

extern "C" void kernel_launch(void* const* d_in, const int* in_sizes, int n_in,
                              void* d_out, int out_size, void* d_ws, size_t ws_size,
                              hipStream_t stream) {
    const float* q  = (const float*)d_in[0];
    const float* k  = (const float*)d_in[1];
    const float* W1 = (const float*)d_in[2];
    const float* b1 = (const float*)d_in[3];
    const float* W2 = (const float*)d_in[4];
    const float* b2 = (const float*)d_in[5];
    float* out = (float*)d_out;

    h2* qh_h = (h2*)d_ws;
    h2* kh_h = qh_h + (size_t)NBH * NP * T;

    proj_kernel<<<512, 256, 0, stream>>>(q, k, W1, b1, qh_h, kh_h);
    score_kernel<<<1024, 128, 0, stream>>>(qh_h, kh_h, W2, b2, out);
}